// Round 3
// baseline (349.955 us; speedup 1.0000x reference)
//
#include <hip/hip_runtime.h>
#include <stdint.h>

// BMM: out[b,m,n] = round(alpha * sum_k a[b,m,k]*b[b,n,k]), int8 x int8 -> int32
// B=64, M=1024, N=1024, K=128.
//
// HARNESS CONVENTION: integer inputs are delivered as int32 buffers (one
// int32 per logical int8 element, values in [-128,127]). R0/R1 read them as
// packed int8 -> identical deterministic garbage. R2 reads int32 and packs
// the low bytes into int8 granules during staging.
//
// Write-bound: 256 MB output vs ~67 MB int32 inputs vs ~4 us of i8 MFMA.
// One 128x128 C-tile per block; K=128 staged entirely into LDS (no K-loop).
// XOR-swizzled LDS rows -> conflict-free ds_read_b128 fragment reads.

typedef int v4i  __attribute__((ext_vector_type(4)));
typedef int v16i __attribute__((ext_vector_type(16)));

__device__ __forceinline__ int pack4(v4i w) {
    // low bytes of 4 int32 lanes -> one dword of 4 int8 (two's complement)
    return (w.x & 0xFF) | ((w.y & 0xFF) << 8) | ((w.z & 0xFF) << 16) | (w.w << 24);
}

__global__ __launch_bounds__(256, 2) void bmm_s8s8_s32_kernel(
    const int*   __restrict__ A,     // [64,1024,128] int32-expanded int8
    const int*   __restrict__ Bm,    // [64,1024,128] int32-expanded int8
    const float* __restrict__ alpha_p,
    int*         __restrict__ out)   // [64,1024,1024]
{
    __shared__ uint8_t Als[128 * 128];
    __shared__ uint8_t Bls[128 * 128];

    const int tid   = threadIdx.x;
    const int lane  = tid & 63;
    const int wave  = tid >> 6;        // 0..3
    const int half_ = lane >> 5;       // 0..1
    const int lrow  = lane & 31;       // 0..31

    const int bz = blockIdx.z;
    const int m0 = blockIdx.y << 7;
    const int n0 = blockIdx.x << 7;

    // Tile bases in int32 elements; each row = 128 int32 = 512 B.
    const size_t abase = ((size_t)bz * 1024 + (size_t)m0) * 128;
    const size_t bbase = ((size_t)bz * 1024 + (size_t)n0) * 128;

    // ---- Stage: granule = 16 k-values = 64 B of int32 = 4 dwordx4 loads,
    //      packed to 16 int8, stored at swizzled slot gp^(m&7) of row m.
#pragma unroll
    for (int t = 0; t < 4; ++t) {
        const int G  = t * 256 + tid;              // granule 0..1023
        const int m  = G >> 3;                     // row in tile
        const int gp = G & 7;                      // granule slot in row
        const size_t goff = (size_t)m * 128 + (size_t)gp * 16;

        v4i a0 = *(const v4i*)(A + abase + goff + 0);
        v4i a1 = *(const v4i*)(A + abase + goff + 4);
        v4i a2 = *(const v4i*)(A + abase + goff + 8);
        v4i a3 = *(const v4i*)(A + abase + goff + 12);
        v4i b0 = *(const v4i*)(Bm + bbase + goff + 0);
        v4i b1 = *(const v4i*)(Bm + bbase + goff + 4);
        v4i b2 = *(const v4i*)(Bm + bbase + goff + 8);
        v4i b3 = *(const v4i*)(Bm + bbase + goff + 12);

        v4i pa = { pack4(a0), pack4(a1), pack4(a2), pack4(a3) };
        v4i pb = { pack4(b0), pack4(b1), pack4(b2), pack4(b3) };

        const int loff = m * 128 + ((gp ^ (m & 7)) << 4);
        *(v4i*)(Als + loff) = pa;
        *(v4i*)(Bls + loff) = pb;
    }
    __syncthreads();

    // ---- Compute: wave -> 64x64 quadrant; 2x2 of 32x32 MFMA tiles; 4 K-steps.
    const int wr    = wave >> 1;
    const int wc    = wave & 1;
    const int arow0 = wr * 64;
    const int brow0 = wc * 64;

    v16i acc[2][2] = {};

#pragma unroll
    for (int kk = 0; kk < 4; ++kk) {
        const int g = kk * 2 + half_;  // 16B k-granule this half-wave needs
        v4i af[2], bf[2];
#pragma unroll
        for (int mi = 0; mi < 2; ++mi) {
            const int m = arow0 + mi * 32 + lrow;
            af[mi] = *(const v4i*)(Als + m * 128 + ((g ^ (m & 7)) << 4));
        }
#pragma unroll
        for (int ni = 0; ni < 2; ++ni) {
            const int n = brow0 + ni * 32 + lrow;
            bf[ni] = *(const v4i*)(Bls + n * 128 + ((g ^ (n & 7)) << 4));
        }
#pragma unroll
        for (int mi = 0; mi < 2; ++mi)
#pragma unroll
            for (int ni = 0; ni < 2; ++ni)
                acc[mi][ni] = __builtin_amdgcn_mfma_i32_32x32x32_i8(
                    af[mi], bf[ni], acc[mi][ni], 0, 0, 0);
    }

    // ---- Epilogue: scale, round-nearest-even, store int32.
    // C/D layout (32x32, HW-verified): col = lane&31,
    //   row = (reg&3) + 8*(reg>>2) + 4*(lane>>5)
    const float alpha = *alpha_p;
    int* outb = out + ((size_t)bz << 20);

#pragma unroll
    for (int mi = 0; mi < 2; ++mi) {
#pragma unroll
        for (int ni = 0; ni < 2; ++ni) {
            const int gcol = n0 + brow0 + ni * 32 + lrow;
#pragma unroll
            for (int r = 0; r < 16; ++r) {
                const int row  = (r & 3) + 8 * (r >> 2) + 4 * half_;
                const int grow = m0 + arow0 + mi * 32 + row;
                outb[(size_t)grow * 1024 + gcol] =
                    __float2int_rn((float)acc[mi][ni][r] * alpha);
            }
        }
    }
}

extern "C" void kernel_launch(void* const* d_in, const int* in_sizes, int n_in,
                              void* d_out, int out_size, void* d_ws, size_t ws_size,
                              hipStream_t stream) {
    const int*   A     = (const int*)d_in[0];
    const int*   Bm    = (const int*)d_in[1];
    const float* alpha = (const float*)d_in[2];
    int*         out   = (int*)d_out;

    dim3 grid(8, 8, 64);   // n-tiles, m-tiles, batch
    dim3 block(256);
    bmm_s8s8_s32_kernel<<<grid, block, 0, stream>>>(A, Bm, alpha, out);
}